// Round 9
// baseline (263.235 us; speedup 1.0000x reference)
//
#include <hip/hip_runtime.h>
#include <hip/hip_bf16.h>

// Problem constants
#define NPIX 12544   // 112*112
#define NKV 196      // 14*14
#define CCH 64

typedef _Float16 half2_t __attribute__((ext_vector_type(2)));
typedef __fp16 fp16v2_t __attribute__((ext_vector_type(2)));

#if defined(__has_builtin)
#if __has_builtin(__builtin_amdgcn_fdot2)
#define HAVE_FDOT2 1
#endif
#if __has_builtin(__builtin_amdgcn_cvt_pkrtz)
#define HAVE_PKRTZ 1
#endif
#if __has_builtin(__builtin_amdgcn_exp2f)
#define HAVE_EXP2 1
#endif
#endif

__device__ __forceinline__ float dot2acc(half2_t a, half2_t b, float c) {
#ifdef HAVE_FDOT2
  return __builtin_amdgcn_fdot2(a, b, c, false);
#else
  return c + (float)a.x * (float)b.x + (float)a.y * (float)b.y;
#endif
}

__device__ __forceinline__ half2_t pack2(float a, float b) {
#ifdef HAVE_PKRTZ
  union { fp16v2_t r; half2_t h; } u;
  u.r = __builtin_amdgcn_cvt_pkrtz(a, b);
  return u.h;
#else
  half2_t v; v.x = (_Float16)a; v.y = (_Float16)b; return v;
#endif
}

__device__ __forceinline__ half2_t as_h2(uint u) {
  union { uint v; half2_t h; } c; c.v = u; return c.h;
}
__device__ __forceinline__ uint h2u(half2_t h) {
  union { half2_t h; uint v; } c; c.h = h; return c.v;
}
__device__ __forceinline__ float fexp2(float x) {
#ifdef HAVE_EXP2
  return __builtin_amdgcn_exp2f(x);
#else
  return exp2f(x);
#endif
}

// q scale: hd^-0.5 * log2(e) so the softmax can use raw exp2 (v_exp_f32)
#define QSCALE 0.5100974012336431f

// ---------------------------------------------------------------------------
// Prep kernel:
//   blocks 0..783    transpose x1/x2 [B,C,HW]->[B,HW,C]
//   blocks 784..1039 srw [co][ci][ij] -> wt [ij][ci][co]
//   block 1040       combined final weights (fpw@pw4) -> pwh[3] (f16) + pbc
//   blocks 1041..1043 pwv[a] -> pwh[a] f16 packed [c2][co]  (a = blk-1041)
__global__ __launch_bounds__(256) void k_prep(
    const float* __restrict__ x1, const float* __restrict__ x2,
    float* __restrict__ x1f, float* __restrict__ x2f,
    const float* __restrict__ s0, const float* __restrict__ s1,
    const float* __restrict__ s2, const float* __restrict__ s3,
    float* __restrict__ wt,
    const float* __restrict__ fpw, const float* __restrict__ fpb,
    const float* __restrict__ pw4, const float* __restrict__ pb4,
    const float* __restrict__ pw0, const float* __restrict__ pw1,
    const float* __restrict__ pw2,
    uint* __restrict__ pwh, float* __restrict__ pbc) {
  __shared__ float smem[2 * 64 * 65 + 64];
  int blk = blockIdx.x, t = threadIdx.x;
  float (*tile)[65] = (float(*)[65])smem;
  if (blk < 784) {
    int tensor = blk / 392; int rem = blk - tensor * 392;
    int b = rem / 196; int t64 = rem % 196; int n0 = t64 * 64;
    const float* src = tensor ? x2 : x1;
    float* dst = tensor ? x2f : x1f;
    for (int i = 0; i < 16; ++i) {
      int c = i * 4 + (t >> 6);
      int n = t & 63;
      tile[c][n] = src[(b * 64 + c) * NPIX + n0 + n];
    }
    __syncthreads();
    for (int i = 0; i < 16; ++i) {
      int n = i * 4 + (t >> 6);
      int c = t & 63;
      dst[(b * NPIX + n0 + n) * 64 + c] = tile[c][n];
    }
  } else if (blk < 1040) {
    int id = blk - 784; int a = id >> 6; int ci = id & 63;
    const float* s = (a == 0) ? s0 : (a == 1) ? s1 : (a == 2) ? s2 : s3;
    float* d = wt + a * 262144;
    for (int i = 0; i < 16; ++i) {
      int co = i * 4 + (t >> 6);
      int ij = t & 63;
      tile[co][ij] = s[co * 4096 + ci * 64 + ij];
    }
    __syncthreads();
    for (int i = 0; i < 16; ++i) {
      int ij = i * 4 + (t >> 6);
      int co = t & 63;
      d[(ij * 64 + ci) * 64 + co] = tile[co][ij];
    }
  } else if (blk == 1040) {
    float (*A)[65] = (float(*)[65])smem;
    float (*B)[65] = (float(*)[65])(smem + 4160);
    float* bb = smem + 8320;
    for (int i = 0; i < 16; ++i) {
      int idx = i * 256 + t;
      A[idx >> 6][idx & 63] = fpw[idx];
      B[idx >> 6][idx & 63] = pw4[idx];
    }
    if (t < 64) bb[t] = pb4[t];
    __syncthreads();
    int i = t >> 2, jq = t & 3;        // i = final out-channel, cols jq*16..+15
    float acc[16];
#pragma unroll
    for (int jj = 0; jj < 16; ++jj) acc[jj] = 0.f;
    for (int k = 0; k < 64; ++k) {
      float a = A[i][k];
#pragma unroll
      for (int jj = 0; jj < 16; ++jj) acc[jj] += a * B[k][jq * 16 + jj];
    }
    // pack combined weights to f16 [c2][co] layout (slot 3)
#pragma unroll
    for (int m = 0; m < 8; ++m)
      pwh[3 * 2048 + (jq * 8 + m) * 64 + i] = h2u(pack2(acc[2 * m], acc[2 * m + 1]));
    if (t < 64) {
      float s = fpb[t];
      for (int k = 0; k < 64; ++k) s += A[t][k] * bb[k];
      pbc[t] = s;
    }
  } else {
    int a = blk - 1041;                 // 0..2
    const float* pw = (a == 0) ? pw0 : (a == 1) ? pw1 : pw2;
    for (int i = 0; i < 8; ++i) {
      int idx = i * 256 + t;            // 2048 pair-entries
      int co = idx & 63, c2 = idx >> 6;
      float2 wv = *(const float2*)(pw + co * 64 + c2 * 2);
      pwh[a * 2048 + c2 * 64 + co] = h2u(pack2(wv.x, wv.y));
    }
  }
}

// ---------------------------------------------------------------------------
// Reduction conv as GEMM partials.  grid = 49 pixel-groups * 8 k-slices.
__global__ __launch_bounds__(256) void k_conv(
    const float* __restrict__ xf, const float* __restrict__ wt,
    float* __restrict__ part) {
  __shared__ __align__(16) float act[8 * 8 * 72];  // [pix][ijl][ci] pad-72
  __shared__ float red[16][8][65];
  int g = blockIdx.x % 49, s = blockIdx.x / 49;
  int t = threadIdx.x;
  for (int q = 0; q < 5; ++q) {
    int fi = q * 256 + t;                // float4 slots over 8*8*18
    if (fi < 1152) {
      int row = fi / 18, pos = fi % 18;
      if (pos < 16) {
        int pix = row >> 3, ijl = row & 7;
        int ij = s * 8 + ijl, ii = ij >> 3, jj = ij & 7;
        int p = g * 8 + pix, b = p / 196, pi = p % 196;
        int py = pi / 14, px = pi % 14;
        *(float4*)&act[row * 72 + pos * 4] =
            *(const float4*)(xf + (size_t)(b * NPIX + (8 * py + ii) * 112 + 8 * px + jj) * 64 + pos * 4);
      }
    }
  }
  __syncthreads();
  int coq = t & 15, kp = t >> 4;           // kp 0..15
  int ijl = kp >> 1, ci0 = (kp & 1) * 32;
  float acc[8][4];
#pragma unroll
  for (int p = 0; p < 8; ++p)
#pragma unroll
    for (int c = 0; c < 4; ++c) acc[p][c] = 0.f;
  const float* wb = wt + ((s * 8 + ijl) * 64 + ci0) * 64 + coq * 4;
  const float* ab = act + ijl * 72 + ci0;
  for (int kk = 0; kk < 32; ++kk) {
    float4 w4 = *(const float4*)(wb + kk * 64);
#pragma unroll
    for (int p = 0; p < 8; ++p) {
      float a = ab[p * 576 + kk];
      acc[p][0] += a * w4.x; acc[p][1] += a * w4.y;
      acc[p][2] += a * w4.z; acc[p][3] += a * w4.w;
    }
  }
#pragma unroll
  for (int p = 0; p < 8; ++p)
#pragma unroll
    for (int c = 0; c < 4; ++c) red[kp][p][coq * 4 + c] = acc[p][c];
  __syncthreads();
  for (int q = 0; q < 2; ++q) {
    int oi = t + q * 256;
    int pix = oi >> 6, co = oi & 63;
    float sum = 0.f;
#pragma unroll
    for (int k = 0; k < 16; ++k) sum += red[k][pix][co];
    int p = g * 8 + pix;
    part[(s * 392 + p) * 64 + co] = sum;
  }
}

// ---------------------------------------------------------------------------
// Reduce conv partials, +bias, LayerNorm, KV projection -> f16 K,V.
__global__ __launch_bounds__(128) void k_lnkv(
    const float* __restrict__ part, const float* __restrict__ srb,
    const float* __restrict__ lng, const float* __restrict__ lnb,
    const float* __restrict__ kvw,
    _Float16* __restrict__ kbuf, _Float16* __restrict__ vbuf) {
  __shared__ __align__(16) float yn[64];
  __shared__ __align__(16) float4 lkvw[16][128];   // [ci4][co2] vectorized
  int p = blockIdx.x, t = threadIdx.x;
  for (int i = 0; i < 64; ++i) {
    int idx = i * 128 + t;
    int co2 = idx >> 6, ci = idx & 63;
    ((float*)lkvw)[(ci >> 2) * 512 + co2 * 4 + (ci & 3)] = kvw[idx];
  }
  if (t < 64) {
    float y = 0.f;
    for (int s = 0; s < 8; ++s) y += part[(s * 392 + p) * 64 + t];
    y += srb[t];
    float s1 = y, s2 = y * y;
#pragma unroll
    for (int off = 32; off; off >>= 1) { s1 += __shfl_xor(s1, off); s2 += __shfl_xor(s2, off); }
    float mean = s1 * 0.015625f;
    float var = s2 * 0.015625f - mean * mean;
    float rs = rsqrtf(var + 1e-5f);
    yn[t] = (y - mean) * rs * lng[t] + lnb[t];
  }
  __syncthreads();
  float acc = 0.f;
#pragma unroll
  for (int c4 = 0; c4 < 16; ++c4) {
    float4 w4 = lkvw[c4][t];
    float4 y4 = *(const float4*)&yn[c4 * 4];
    acc += y4.x * w4.x + y4.y * w4.y + y4.z * w4.z + y4.w * w4.w;
  }
  int b = p / 196, pi = p % 196;
  int h = (t & 63) >> 3, d = t & 7;
  if (t < 64) kbuf[((b * 8 + h) * 196 + pi) * 8 + d] = (_Float16)acc;          // [b][h][m][d]
  else        vbuf[((b * 8 + h) * 8 + d) * 196 + pi] = (_Float16)acc;          // [b][h][d][m]
}

// ---------------------------------------------------------------------------
// Fused q-proj + attention core + residual + out-projection, m-SPLIT.
// grid = 392 blocks (64-row tiles), 512 threads: t = mg*256 + r*8 + h,
// mg in {0,1} covers m4 range [0,25) / [25,49); each thread 2 rows (r, r+32).
// R8 post-mortem: latency-bound at 6 waves/CU; this doubles resident waves
// (3136 total, ~12/CU) while halving each wave's m-loop critical path.
// mg=1 stores f16 partials (o8,l) to sP; mg=0 combines -> sU; out-proj
// splits 1 row/thread.  LDS 69.6 KB -> 2 blocks/CU.
template <bool FINAL>
__global__ __launch_bounds__(512, 4) void k_score_out(
    const float* __restrict__ xqf, const float* __restrict__ qw,
    const _Float16* __restrict__ kbuf, const _Float16* __restrict__ vbuf,
    const uint* __restrict__ pwh, const float* __restrict__ pb,
    float* __restrict__ outp) {
  __shared__ __align__(16) uint4 sK[8 * 197];   // 25216 B, bank h*20
  __shared__ __align__(16) uint sV[8 * 804];    // 25728 B, bank h*4
  __shared__ __align__(16) uint sU[64 * 33];    //  8448 B, qw then o-rows
  __shared__ __align__(16) uint sPo[512 * 4];   //  8192 B, o8 partials (f16)
  __shared__ float sPl[512];                    //  2048 B, l partials
  int blk = blockIdx.x;
  int b = blk / 196, tileb = blk % 196;
  int t = threadIdx.x;
  int mg = t >> 8, tl = t & 255;
  int r = tl >> 3, h = tl & 7;
  // --- stage K (all 8 heads of batch b) ---
  const uint4* kg = (const uint4*)kbuf + (size_t)b * 1568;
  for (int i = t; i < 1568; i += 512) {
    int hh = i / 196, m = i - hh * 196;
    sK[hh * 197 + m] = kg[i];
  }
  // --- stage V ---
  const uint* vg = (const uint*)vbuf + (size_t)b * 6272;
  for (int i = t; i < 6272; i += 512) {
    int hh = i / 784, r2 = i - hh * 784;
    sV[hh * 804 + r2] = vg[i];
  }
  // --- stage q-weights f16, QSCALE folded, [c2][co] ---
  for (int i = t; i < 2048; i += 512) {
    int co = i & 63, c2 = i >> 6;
    float2 wv = *(const float2*)(qw + co * 64 + c2 * 2);
    sU[c2 * 64 + co] = h2u(pack2(wv.x * QSCALE, wv.y * QSCALE));
  }
  // --- own 2 xq rows -> f16-pair regs ---
  size_t gr0 = (size_t)b * NPIX + (size_t)tileb * 64 + r;
  size_t gr1 = gr0 + 32;
  uint xh0[32], xh1[32];
  {
    const float2* x0 = (const float2*)(xqf + gr0 * 64);
    const float2* x1 = (const float2*)(xqf + gr1 * 64);
#pragma unroll
    for (int i = 0; i < 32; ++i) { float2 v = x0[i]; xh0[i] = h2u(pack2(v.x, v.y)); }
#pragma unroll
    for (int i = 0; i < 32; ++i) { float2 v = x1[i]; xh1[i] = h2u(pack2(v.x, v.y)); }
  }
  __syncthreads();
  // --- q projection for both rows (redundant across mg; off critical LDS) ---
  float q80[8], q81[8];
#pragma unroll
  for (int j = 0; j < 8; ++j) { q80[j] = 0.f; q81[j] = 0.f; }
#pragma unroll
  for (int c2 = 0; c2 < 32; ++c2) {
    half2_t xv0 = as_h2(xh0[c2]), xv1 = as_h2(xh1[c2]);
    uint4 w0 = *(const uint4*)&sU[c2 * 64 + h * 8];
    uint4 w1 = *(const uint4*)&sU[c2 * 64 + h * 8 + 4];
    q80[0] = dot2acc(xv0, as_h2(w0.x), q80[0]); q81[0] = dot2acc(xv1, as_h2(w0.x), q81[0]);
    q80[1] = dot2acc(xv0, as_h2(w0.y), q80[1]); q81[1] = dot2acc(xv1, as_h2(w0.y), q81[1]);
    q80[2] = dot2acc(xv0, as_h2(w0.z), q80[2]); q81[2] = dot2acc(xv1, as_h2(w0.z), q81[2]);
    q80[3] = dot2acc(xv0, as_h2(w0.w), q80[3]); q81[3] = dot2acc(xv1, as_h2(w0.w), q81[3]);
    q80[4] = dot2acc(xv0, as_h2(w1.x), q80[4]); q81[4] = dot2acc(xv1, as_h2(w1.x), q81[4]);
    q80[5] = dot2acc(xv0, as_h2(w1.y), q80[5]); q81[5] = dot2acc(xv1, as_h2(w1.y), q81[5]);
    q80[6] = dot2acc(xv0, as_h2(w1.z), q80[6]); q81[6] = dot2acc(xv1, as_h2(w1.z), q81[6]);
    q80[7] = dot2acc(xv0, as_h2(w1.w), q80[7]); q81[7] = dot2acc(xv1, as_h2(w1.w), q81[7]);
  }
  half2_t qh0[4], qh1[4];
#pragma unroll
  for (int i = 0; i < 4; ++i) {
    qh0[i] = pack2(q80[2 * i], q80[2 * i + 1]);
    qh1[i] = pack2(q81[2 * i], q81[2 * i + 1]);
  }
  __syncthreads();   // lqw reads done; sU becomes lo
  // --- max-free online softmax over this mg's m-half, 2 rows per thread ---
  const uint4* kp = &sK[h * 197];
  const uint* vp = &sV[h * 804];
  float l0 = 0.f, l1 = 0.f;
  float o80[8], o81[8];
#pragma unroll
  for (int j = 0; j < 8; ++j) { o80[j] = 0.f; o81[j] = 0.f; }
  int m4b = mg ? 25 : 0, m4e = mg ? 49 : 25;
  for (int m4 = m4b; m4 < m4e; ++m4) {
    union { uint4 u; half2_t h2[4]; } k0, k1, k2, k3;
    k0.u = kp[4 * m4 + 0]; k1.u = kp[4 * m4 + 1];
    k2.u = kp[4 * m4 + 2]; k3.u = kp[4 * m4 + 3];
    float s00 = 0.f, s01 = 0.f, s02 = 0.f, s03 = 0.f;
    float s10 = 0.f, s11 = 0.f, s12 = 0.f, s13 = 0.f;
#pragma unroll
    for (int i = 0; i < 4; ++i) {
      s00 = dot2acc(qh0[i], k0.h2[i], s00); s10 = dot2acc(qh1[i], k0.h2[i], s10);
      s01 = dot2acc(qh0[i], k1.h2[i], s01); s11 = dot2acc(qh1[i], k1.h2[i], s11);
      s02 = dot2acc(qh0[i], k2.h2[i], s02); s12 = dot2acc(qh1[i], k2.h2[i], s12);
      s03 = dot2acc(qh0[i], k3.h2[i], s03); s13 = dot2acc(qh1[i], k3.h2[i], s13);
    }
    float e00 = fexp2(s00), e01 = fexp2(s01), e02 = fexp2(s02), e03 = fexp2(s03);
    float e10 = fexp2(s10), e11 = fexp2(s11), e12 = fexp2(s12), e13 = fexp2(s13);
    l0 += (e00 + e01) + (e02 + e03);
    l1 += (e10 + e11) + (e12 + e13);
    half2_t ep01_0 = pack2(e00, e01), ep23_0 = pack2(e02, e03);
    half2_t ep01_1 = pack2(e10, e11), ep23_1 = pack2(e12, e13);
#pragma unroll
    for (int d = 0; d < 8; ++d) {
      uint2 vv = *(const uint2*)&vp[d * 98 + 2 * m4];
      half2_t va = as_h2(vv.x), vb = as_h2(vv.y);
      o80[d] = dot2acc(ep01_0, va, o80[d]);
      o80[d] = dot2acc(ep23_0, vb, o80[d]);
      o81[d] = dot2acc(ep01_1, va, o81[d]);
      o81[d] = dot2acc(ep23_1, vb, o81[d]);
    }
  }
  // --- combine halves: mg=1 stores partials; mg=0 merges, writes sU ---
  if (mg == 1) {
    uint4 p0, p1;
    p0.x = h2u(pack2(o80[0], o80[1])); p0.y = h2u(pack2(o80[2], o80[3]));
    p0.z = h2u(pack2(o80[4], o80[5])); p0.w = h2u(pack2(o80[6], o80[7]));
    p1.x = h2u(pack2(o81[0], o81[1])); p1.y = h2u(pack2(o81[2], o81[3]));
    p1.z = h2u(pack2(o81[4], o81[5])); p1.w = h2u(pack2(o81[6], o81[7]));
    *(uint4*)&sPo[tl * 4] = p0;
    *(uint4*)&sPo[(tl + 256) * 4] = p1;
    sPl[tl] = l0;
    sPl[tl + 256] = l1;
  }
  __syncthreads();
  if (mg == 0) {
    uint4 p0 = *(const uint4*)&sPo[tl * 4];
    uint4 p1 = *(const uint4*)&sPo[(tl + 256) * 4];
    float rl0 = 1.f / (l0 + sPl[tl]);
    float rl1 = 1.f / (l1 + sPl[tl + 256]);
    half2_t a0 = as_h2(p0.x), a1 = as_h2(p0.y), a2 = as_h2(p0.z), a3 = as_h2(p0.w);
    sU[r * 33 + h * 4 + 0] = h2u(pack2((o80[0] + (float)a0.x) * rl0, (o80[1] + (float)a0.y) * rl0));
    sU[r * 33 + h * 4 + 1] = h2u(pack2((o80[2] + (float)a1.x) * rl0, (o80[3] + (float)a1.y) * rl0));
    sU[r * 33 + h * 4 + 2] = h2u(pack2((o80[4] + (float)a2.x) * rl0, (o80[5] + (float)a2.y) * rl0));
    sU[r * 33 + h * 4 + 3] = h2u(pack2((o80[6] + (float)a3.x) * rl0, (o80[7] + (float)a3.y) * rl0));
    half2_t b0 = as_h2(p1.x), b1 = as_h2(p1.y), b2 = as_h2(p1.z), b3 = as_h2(p1.w);
    sU[(r + 32) * 33 + h * 4 + 0] = h2u(pack2((o81[0] + (float)b0.x) * rl1, (o81[1] + (float)b0.y) * rl1));
    sU[(r + 32) * 33 + h * 4 + 1] = h2u(pack2((o81[2] + (float)b1.x) * rl1, (o81[3] + (float)b1.y) * rl1));
    sU[(r + 32) * 33 + h * 4 + 2] = h2u(pack2((o81[4] + (float)b2.x) * rl1, (o81[5] + (float)b2.y) * rl1));
    sU[(r + 32) * 33 + h * 4 + 3] = h2u(pack2((o81[6] + (float)b3.x) * rl1, (o81[7] + (float)b3.y) * rl1));
  }
  __syncthreads();
  // --- residual + out-projection: 1 row per thread (mg picks the row) ---
  int rowm = mg ? (r + 32) : r;
  size_t grm = mg ? gr1 : gr0;
  const uint* xhm = mg ? xh1 : xh0;
  int cg = h;
  float acc[8];
#pragma unroll
  for (int k = 0; k < 8; ++k) acc[k] = pb[cg * 8 + k];
#pragma unroll
  for (int c2 = 0; c2 < 32; ++c2) {
    half2_t sv = as_h2(sU[rowm * 33 + c2]) + as_h2(xhm[c2]);
    uint4 w0 = *(const uint4*)&pwh[c2 * 64 + cg * 8];
    uint4 w1 = *(const uint4*)&pwh[c2 * 64 + cg * 8 + 4];
    acc[0] = dot2acc(sv, as_h2(w0.x), acc[0]);
    acc[1] = dot2acc(sv, as_h2(w0.y), acc[1]);
    acc[2] = dot2acc(sv, as_h2(w0.z), acc[2]);
    acc[3] = dot2acc(sv, as_h2(w0.w), acc[3]);
    acc[4] = dot2acc(sv, as_h2(w1.x), acc[4]);
    acc[5] = dot2acc(sv, as_h2(w1.y), acc[5]);
    acc[6] = dot2acc(sv, as_h2(w1.z), acc[6]);
    acc[7] = dot2acc(sv, as_h2(w1.w), acc[7]);
  }
  if (!FINAL) {
    float* orow = outp + grm * 64 + cg * 8;
    float4 v0, v1;
    v0.x = acc[0]; v0.y = acc[1]; v0.z = acc[2]; v0.w = acc[3];
    v1.x = acc[4]; v1.y = acc[5]; v1.z = acc[6]; v1.w = acc[7];
    *(float4*)orow = v0;
    *(float4*)(orow + 4) = v1;
  } else {
    // stage final rows as f16 pairs into sPo ([64][33] layout), then NCHW store
#pragma unroll
    for (int j = 0; j < 4; ++j)
      sPo[rowm * 33 + cg * 4 + j] = h2u(pack2(acc[2 * j], acc[2 * j + 1]));
    __syncthreads();
    for (int i = t; i < 4096; i += 512) {
      int c = i >> 6, rr = i & 63;
      half2_t pr = as_h2(sPo[rr * 33 + (c >> 1)]);
      float val = (c & 1) ? (float)pr.y : (float)pr.x;
      outp[((size_t)(b * 64 + c)) * NPIX + (size_t)tileb * 64 + rr] = val;
    }
  }
}

// ---------------------------------------------------------------------------
extern "C" void kernel_launch(void* const* d_in, const int* in_sizes, int n_in,
                              void* d_out, int out_size, void* d_ws, size_t ws_size,
                              hipStream_t stream) {
  const float* x1 = (const float*)d_in[0];
  const float* x2 = (const float*)d_in[1];
  const float *qw[4], *kvw[4], *pwv[4], *pbv[4], *srw[4], *srb[4], *lng[4], *lnb[4];
  for (int i = 0; i < 4; ++i) {
    const int base = 2 + i * 8;
    qw[i]  = (const float*)d_in[base + 0];
    kvw[i] = (const float*)d_in[base + 1];
    pwv[i] = (const float*)d_in[base + 2];
    pbv[i] = (const float*)d_in[base + 3];
    srw[i] = (const float*)d_in[base + 4];
    srb[i] = (const float*)d_in[base + 5];
    lng[i] = (const float*)d_in[base + 6];
    lnb[i] = (const float*)d_in[base + 7];
  }
  const float* fpw = (const float*)d_in[34];
  const float* fpb = (const float*)d_in[35];
  float* out = (float*)d_out;

  char* ws = (char*)d_ws;
  const size_t SZ = (size_t)2 * NPIX * 64 * 4;       // 6,422,528 B
  float* slot0 = (float*)(ws);
  float* slot1 = (float*)(ws + SZ);
  float* slot2 = (float*)(ws + 2 * SZ);
  size_t off = 3 * SZ;
  float* wt    = (float*)(ws + off); off += 4u * 1048576;
  float* part  = (float*)(ws + off); off += 802816;
  _Float16* kbuf = (_Float16*)(ws + off); off += 50176;
  _Float16* vbuf = (_Float16*)(ws + off); off += 50176;
  uint* pwh    = (uint*)(ws + off); off += 4 * 2048 * 4;
  float* pbc   = (float*)(ws + off); off += 256;

  float* xf1 = slot0; float* xf2 = slot1;
  float* abuf = slot2; float* bbuf = slot0; float* cbuf = slot1;

  k_prep<<<1044, 256, 0, stream>>>(x1, x2, xf1, xf2,
                                   srw[0], srw[1], srw[2], srw[3], wt,
                                   fpw, fpb, pwv[3], pbv[3],
                                   pwv[0], pwv[1], pwv[2], pwh, pbc);

  const float* xqs[4] = {xf1, xf2, bbuf, abuf};
  const float* kvs[4] = {xf1, abuf, bbuf, cbuf};
  float* outs[3]      = {abuf, bbuf, cbuf};
  for (int i = 0; i < 4; ++i) {
    k_conv<<<392, 256, 0, stream>>>(kvs[i], wt + i * 262144, part);
    k_lnkv<<<392, 128, 0, stream>>>(part, srb[i], lng[i], lnb[i], kvw[i], kbuf, vbuf);
    if (i < 3)
      k_score_out<false><<<392, 512, 0, stream>>>(xqs[i], qw[i], kbuf, vbuf,
                                                  pwh + i * 2048, pbv[i], outs[i]);
    else
      k_score_out<true><<<392, 512, 0, stream>>>(xqs[3], qw[3], kbuf, vbuf,
                                                 pwh + 3 * 2048, pbc, out);
  }
}

// Round 10
// 247.515 us; speedup vs baseline: 1.0635x; 1.0635x over previous
//
#include <hip/hip_runtime.h>
#include <hip/hip_bf16.h>

// Problem constants
#define NPIX 12544   // 112*112
#define NKV 196      // 14*14
#define CCH 64

typedef _Float16 half2_t __attribute__((ext_vector_type(2)));
typedef __fp16 fp16v2_t __attribute__((ext_vector_type(2)));

#if defined(__has_builtin)
#if __has_builtin(__builtin_amdgcn_fdot2)
#define HAVE_FDOT2 1
#endif
#if __has_builtin(__builtin_amdgcn_cvt_pkrtz)
#define HAVE_PKRTZ 1
#endif
#if __has_builtin(__builtin_amdgcn_exp2f)
#define HAVE_EXP2 1
#endif
#endif

__device__ __forceinline__ float dot2acc(half2_t a, half2_t b, float c) {
#ifdef HAVE_FDOT2
  return __builtin_amdgcn_fdot2(a, b, c, false);
#else
  return c + (float)a.x * (float)b.x + (float)a.y * (float)b.y;
#endif
}

__device__ __forceinline__ half2_t pack2(float a, float b) {
#ifdef HAVE_PKRTZ
  union { fp16v2_t r; half2_t h; } u;
  u.r = __builtin_amdgcn_cvt_pkrtz(a, b);
  return u.h;
#else
  half2_t v; v.x = (_Float16)a; v.y = (_Float16)b; return v;
#endif
}

__device__ __forceinline__ half2_t as_h2(uint u) {
  union { uint v; half2_t h; } c; c.v = u; return c.h;
}
__device__ __forceinline__ uint h2u(half2_t h) {
  union { half2_t h; uint v; } c; c.h = h; return c.v;
}
__device__ __forceinline__ float fexp2(float x) {
#ifdef HAVE_EXP2
  return __builtin_amdgcn_exp2f(x);
#else
  return exp2f(x);
#endif
}

// q scale: hd^-0.5 * log2(e) so the softmax can use raw exp2 (v_exp_f32)
#define QSCALE 0.5100974012336431f

// ---------------------------------------------------------------------------
// Prep kernel:
//   blocks 0..783    transpose x1/x2 [B,C,HW]->[B,HW,C]
//   blocks 784..1039 srw [co][ci][ij] -> wt [ij][ci][co]
//   block 1040       combined final weights (fpw@pw4) -> pwh[3] (f16) + pbc
//   blocks 1041..1043 pwv[a] -> pwh[a] f16 packed [c2][co]  (a = blk-1041)
__global__ __launch_bounds__(256) void k_prep(
    const float* __restrict__ x1, const float* __restrict__ x2,
    float* __restrict__ x1f, float* __restrict__ x2f,
    const float* __restrict__ s0, const float* __restrict__ s1,
    const float* __restrict__ s2, const float* __restrict__ s3,
    float* __restrict__ wt,
    const float* __restrict__ fpw, const float* __restrict__ fpb,
    const float* __restrict__ pw4, const float* __restrict__ pb4,
    const float* __restrict__ pw0, const float* __restrict__ pw1,
    const float* __restrict__ pw2,
    uint* __restrict__ pwh, float* __restrict__ pbc) {
  __shared__ float smem[2 * 64 * 65 + 64];
  int blk = blockIdx.x, t = threadIdx.x;
  float (*tile)[65] = (float(*)[65])smem;
  if (blk < 784) {
    int tensor = blk / 392; int rem = blk - tensor * 392;
    int b = rem / 196; int t64 = rem % 196; int n0 = t64 * 64;
    const float* src = tensor ? x2 : x1;
    float* dst = tensor ? x2f : x1f;
    for (int i = 0; i < 16; ++i) {
      int c = i * 4 + (t >> 6);
      int n = t & 63;
      tile[c][n] = src[(b * 64 + c) * NPIX + n0 + n];
    }
    __syncthreads();
    for (int i = 0; i < 16; ++i) {
      int n = i * 4 + (t >> 6);
      int c = t & 63;
      dst[(b * NPIX + n0 + n) * 64 + c] = tile[c][n];
    }
  } else if (blk < 1040) {
    int id = blk - 784; int a = id >> 6; int ci = id & 63;
    const float* s = (a == 0) ? s0 : (a == 1) ? s1 : (a == 2) ? s2 : s3;
    float* d = wt + a * 262144;
    for (int i = 0; i < 16; ++i) {
      int co = i * 4 + (t >> 6);
      int ij = t & 63;
      tile[co][ij] = s[co * 4096 + ci * 64 + ij];
    }
    __syncthreads();
    for (int i = 0; i < 16; ++i) {
      int ij = i * 4 + (t >> 6);
      int co = t & 63;
      d[(ij * 64 + ci) * 64 + co] = tile[co][ij];
    }
  } else if (blk == 1040) {
    float (*A)[65] = (float(*)[65])smem;
    float (*B)[65] = (float(*)[65])(smem + 4160);
    float* bb = smem + 8320;
    for (int i = 0; i < 16; ++i) {
      int idx = i * 256 + t;
      A[idx >> 6][idx & 63] = fpw[idx];
      B[idx >> 6][idx & 63] = pw4[idx];
    }
    if (t < 64) bb[t] = pb4[t];
    __syncthreads();
    int i = t >> 2, jq = t & 3;        // i = final out-channel, cols jq*16..+15
    float acc[16];
#pragma unroll
    for (int jj = 0; jj < 16; ++jj) acc[jj] = 0.f;
    for (int k = 0; k < 64; ++k) {
      float a = A[i][k];
#pragma unroll
      for (int jj = 0; jj < 16; ++jj) acc[jj] += a * B[k][jq * 16 + jj];
    }
    // pack combined weights to f16 [c2][co] layout (slot 3)
#pragma unroll
    for (int m = 0; m < 8; ++m)
      pwh[3 * 2048 + (jq * 8 + m) * 64 + i] = h2u(pack2(acc[2 * m], acc[2 * m + 1]));
    if (t < 64) {
      float s = fpb[t];
      for (int k = 0; k < 64; ++k) s += A[t][k] * bb[k];
      pbc[t] = s;
    }
  } else {
    int a = blk - 1041;                 // 0..2
    const float* pw = (a == 0) ? pw0 : (a == 1) ? pw1 : pw2;
    for (int i = 0; i < 8; ++i) {
      int idx = i * 256 + t;            // 2048 pair-entries
      int co = idx & 63, c2 = idx >> 6;
      float2 wv = *(const float2*)(pw + co * 64 + c2 * 2);
      pwh[a * 2048 + c2 * 64 + co] = h2u(pack2(wv.x, wv.y));
    }
  }
}

// ---------------------------------------------------------------------------
// Reduction conv as GEMM partials.  grid = 49 pixel-groups * 8 k-slices.
__global__ __launch_bounds__(256) void k_conv(
    const float* __restrict__ xf, const float* __restrict__ wt,
    float* __restrict__ part) {
  __shared__ __align__(16) float act[8 * 8 * 72];  // [pix][ijl][ci] pad-72
  __shared__ float red[16][8][65];
  int g = blockIdx.x % 49, s = blockIdx.x / 49;
  int t = threadIdx.x;
  for (int q = 0; q < 5; ++q) {
    int fi = q * 256 + t;                // float4 slots over 8*8*18
    if (fi < 1152) {
      int row = fi / 18, pos = fi % 18;
      if (pos < 16) {
        int pix = row >> 3, ijl = row & 7;
        int ij = s * 8 + ijl, ii = ij >> 3, jj = ij & 7;
        int p = g * 8 + pix, b = p / 196, pi = p % 196;
        int py = pi / 14, px = pi % 14;
        *(float4*)&act[row * 72 + pos * 4] =
            *(const float4*)(xf + (size_t)(b * NPIX + (8 * py + ii) * 112 + 8 * px + jj) * 64 + pos * 4);
      }
    }
  }
  __syncthreads();
  int coq = t & 15, kp = t >> 4;           // kp 0..15
  int ijl = kp >> 1, ci0 = (kp & 1) * 32;
  float acc[8][4];
#pragma unroll
  for (int p = 0; p < 8; ++p)
#pragma unroll
    for (int c = 0; c < 4; ++c) acc[p][c] = 0.f;
  const float* wb = wt + ((s * 8 + ijl) * 64 + ci0) * 64 + coq * 4;
  const float* ab = act + ijl * 72 + ci0;
  for (int kk = 0; kk < 32; ++kk) {
    float4 w4 = *(const float4*)(wb + kk * 64);
#pragma unroll
    for (int p = 0; p < 8; ++p) {
      float a = ab[p * 576 + kk];
      acc[p][0] += a * w4.x; acc[p][1] += a * w4.y;
      acc[p][2] += a * w4.z; acc[p][3] += a * w4.w;
    }
  }
#pragma unroll
  for (int p = 0; p < 8; ++p)
#pragma unroll
    for (int c = 0; c < 4; ++c) red[kp][p][coq * 4 + c] = acc[p][c];
  __syncthreads();
  for (int q = 0; q < 2; ++q) {
    int oi = t + q * 256;
    int pix = oi >> 6, co = oi & 63;
    float sum = 0.f;
#pragma unroll
    for (int k = 0; k < 16; ++k) sum += red[k][pix][co];
    int p = g * 8 + pix;
    part[(s * 392 + p) * 64 + co] = sum;
  }
}

// ---------------------------------------------------------------------------
// Reduce conv partials, +bias, LayerNorm, KV projection -> f16 K,V.
// V layout CHANGED for scalar-load AV: [b][h][mp][d*2+par] (mp = pixel pair).
__global__ __launch_bounds__(128) void k_lnkv(
    const float* __restrict__ part, const float* __restrict__ srb,
    const float* __restrict__ lng, const float* __restrict__ lnb,
    const float* __restrict__ kvw,
    _Float16* __restrict__ kbuf, _Float16* __restrict__ vbuf) {
  __shared__ __align__(16) float yn[64];
  __shared__ __align__(16) float4 lkvw[16][128];   // [ci4][co2] vectorized
  int p = blockIdx.x, t = threadIdx.x;
  for (int i = 0; i < 64; ++i) {
    int idx = i * 128 + t;
    int co2 = idx >> 6, ci = idx & 63;
    ((float*)lkvw)[(ci >> 2) * 512 + co2 * 4 + (ci & 3)] = kvw[idx];
  }
  if (t < 64) {
    float y = 0.f;
    for (int s = 0; s < 8; ++s) y += part[(s * 392 + p) * 64 + t];
    y += srb[t];
    float s1 = y, s2 = y * y;
#pragma unroll
    for (int off = 32; off; off >>= 1) { s1 += __shfl_xor(s1, off); s2 += __shfl_xor(s2, off); }
    float mean = s1 * 0.015625f;
    float var = s2 * 0.015625f - mean * mean;
    float rs = rsqrtf(var + 1e-5f);
    yn[t] = (y - mean) * rs * lng[t] + lnb[t];
  }
  __syncthreads();
  float acc = 0.f;
#pragma unroll
  for (int c4 = 0; c4 < 16; ++c4) {
    float4 w4 = lkvw[c4][t];
    float4 y4 = *(const float4*)&yn[c4 * 4];
    acc += y4.x * w4.x + y4.y * w4.y + y4.z * w4.z + y4.w * w4.w;
  }
  int b = p / 196, pi = p % 196;
  int h = (t & 63) >> 3, d = t & 7;
  if (t < 64) kbuf[((b * 8 + h) * 196 + pi) * 8 + d] = (_Float16)acc;   // [b][h][m][d]
  else        vbuf[((b * 8 + h) * 98 + (pi >> 1)) * 16 + d * 2 + (pi & 1)] = (_Float16)acc;
}

// ---------------------------------------------------------------------------
// Fused q-proj + attention + residual + out-proj, WAVE-PER-HEAD + scalar K/V.
// grid = 392 (b, 64-row tile), 512 threads = 8 waves; wave h = head h,
// lane r = row r.  K/V addresses are wave-uniform (h via readfirstlane) ->
// compiler emits s_load: the m-loop runs on SMEM+VALU pipes, zero LDS/VMEM.
// LDS only 16.6 KB (qw staging + o-row exchange).
template <bool FINAL>
__global__ __launch_bounds__(512, 2) void k_score_out(
    const float* __restrict__ xqf, const float* __restrict__ qw,
    const _Float16* __restrict__ kbuf, const _Float16* __restrict__ vbuf,
    const uint* __restrict__ pwh, const float* __restrict__ pb,
    float* __restrict__ outp) {
  __shared__ __align__(16) uint sW[2048];      // qw f16 pairs [c2][co]
  __shared__ __align__(16) uint sU[64 * 33];   // o-rows (f16 pairs)
  int blk = blockIdx.x;
  int b = blk / 196, tileb = blk % 196;
  int t = threadIdx.x;
  int h = __builtin_amdgcn_readfirstlane(t >> 6);   // wave-uniform head
  int r = t & 63;                                    // lane = row
  // --- stage q-weights f16, QSCALE folded, [c2][co] ---
  for (int i = t; i < 2048; i += 512) {
    int co = i & 63, c2 = i >> 6;
    float2 wv = *(const float2*)(qw + co * 64 + c2 * 2);
    sW[c2 * 64 + co] = h2u(pack2(wv.x * QSCALE, wv.y * QSCALE));
  }
  // --- own xq row -> 32 f16-pair regs ---
  size_t gr = (size_t)b * NPIX + (size_t)tileb * 64 + r;
  uint xh[32];
  {
    const float2* xs = (const float2*)(xqf + gr * 64);
#pragma unroll
    for (int i = 0; i < 32; ++i) { float2 v = xs[i]; xh[i] = h2u(pack2(v.x, v.y)); }
  }
  __syncthreads();
  // --- q projection (weights uniform per wave -> LDS broadcast) ---
  float q8[8];
#pragma unroll
  for (int j = 0; j < 8; ++j) q8[j] = 0.f;
#pragma unroll
  for (int c2 = 0; c2 < 32; ++c2) {
    half2_t xv = as_h2(xh[c2]);
    uint4 w0 = *(const uint4*)&sW[c2 * 64 + h * 8];
    uint4 w1 = *(const uint4*)&sW[c2 * 64 + h * 8 + 4];
    q8[0] = dot2acc(xv, as_h2(w0.x), q8[0]);
    q8[1] = dot2acc(xv, as_h2(w0.y), q8[1]);
    q8[2] = dot2acc(xv, as_h2(w0.z), q8[2]);
    q8[3] = dot2acc(xv, as_h2(w0.w), q8[3]);
    q8[4] = dot2acc(xv, as_h2(w1.x), q8[4]);
    q8[5] = dot2acc(xv, as_h2(w1.y), q8[5]);
    q8[6] = dot2acc(xv, as_h2(w1.z), q8[6]);
    q8[7] = dot2acc(xv, as_h2(w1.w), q8[7]);
  }
  half2_t qh[4];
#pragma unroll
  for (int i = 0; i < 4; ++i) qh[i] = pack2(q8[2 * i], q8[2 * i + 1]);
  // --- m-loop: K/V via wave-uniform (scalar) loads ---
  const uint4* kp = (const uint4*)kbuf + (size_t)(b * 8 + h) * 196;  // [m][16B]
  const uint4* vp = (const uint4*)vbuf + (size_t)(b * 8 + h) * 196;  // [mp][2x16B]
  float l = 0.f;
  float o8[8];
#pragma unroll
  for (int j = 0; j < 8; ++j) o8[j] = 0.f;
  for (int m4 = 0; m4 < 49; ++m4) {
    union { uint4 u; half2_t h2[4]; } k0, k1, k2, k3;
    k0.u = kp[4 * m4 + 0]; k1.u = kp[4 * m4 + 1];
    k2.u = kp[4 * m4 + 2]; k3.u = kp[4 * m4 + 3];
    uint4 va = vp[4 * m4 + 0], vb_ = vp[4 * m4 + 1];   // mp0: d0-3, d4-7
    uint4 vc = vp[4 * m4 + 2], vd = vp[4 * m4 + 3];    // mp1: d0-3, d4-7
    float s0 = 0.f, s1 = 0.f, s2 = 0.f, s3 = 0.f;
#pragma unroll
    for (int i = 0; i < 4; ++i) {
      s0 = dot2acc(qh[i], k0.h2[i], s0);
      s1 = dot2acc(qh[i], k1.h2[i], s1);
      s2 = dot2acc(qh[i], k2.h2[i], s2);
      s3 = dot2acc(qh[i], k3.h2[i], s3);
    }
    float e0 = fexp2(s0), e1 = fexp2(s1), e2 = fexp2(s2), e3 = fexp2(s3);
    l += (e0 + e1) + (e2 + e3);
    half2_t ep01 = pack2(e0, e1), ep23 = pack2(e2, e3);
    o8[0] = dot2acc(ep01, as_h2(va.x), o8[0]);  o8[0] = dot2acc(ep23, as_h2(vc.x), o8[0]);
    o8[1] = dot2acc(ep01, as_h2(va.y), o8[1]);  o8[1] = dot2acc(ep23, as_h2(vc.y), o8[1]);
    o8[2] = dot2acc(ep01, as_h2(va.z), o8[2]);  o8[2] = dot2acc(ep23, as_h2(vc.z), o8[2]);
    o8[3] = dot2acc(ep01, as_h2(va.w), o8[3]);  o8[3] = dot2acc(ep23, as_h2(vc.w), o8[3]);
    o8[4] = dot2acc(ep01, as_h2(vb_.x), o8[4]); o8[4] = dot2acc(ep23, as_h2(vd.x), o8[4]);
    o8[5] = dot2acc(ep01, as_h2(vb_.y), o8[5]); o8[5] = dot2acc(ep23, as_h2(vd.y), o8[5]);
    o8[6] = dot2acc(ep01, as_h2(vb_.z), o8[6]); o8[6] = dot2acc(ep23, as_h2(vd.z), o8[6]);
    o8[7] = dot2acc(ep01, as_h2(vb_.w), o8[7]); o8[7] = dot2acc(ep23, as_h2(vd.w), o8[7]);
  }
  float rl = 1.f / l;
  // publish normalized o (head h cols) for row r
#pragma unroll
  for (int j = 0; j < 4; ++j)
    sU[r * 33 + h * 4 + j] = h2u(pack2(o8[2 * j] * rl, o8[2 * j + 1] * rl));
  __syncthreads();
  // --- residual + out-proj: wave h computes co = h*8..+7 for its lane's row ---
  float acc[8];
#pragma unroll
  for (int k = 0; k < 8; ++k) acc[k] = pb[h * 8 + k];   // scalar loads
#pragma unroll
  for (int c2 = 0; c2 < 32; ++c2) {
    half2_t sv = as_h2(sU[r * 33 + c2]) + as_h2(xh[c2]);
    uint4 w0 = *(const uint4*)&pwh[c2 * 64 + h * 8];     // uniform -> s_load
    uint4 w1 = *(const uint4*)&pwh[c2 * 64 + h * 8 + 4];
    acc[0] = dot2acc(sv, as_h2(w0.x), acc[0]);
    acc[1] = dot2acc(sv, as_h2(w0.y), acc[1]);
    acc[2] = dot2acc(sv, as_h2(w0.z), acc[2]);
    acc[3] = dot2acc(sv, as_h2(w0.w), acc[3]);
    acc[4] = dot2acc(sv, as_h2(w1.x), acc[4]);
    acc[5] = dot2acc(sv, as_h2(w1.y), acc[5]);
    acc[6] = dot2acc(sv, as_h2(w1.z), acc[6]);
    acc[7] = dot2acc(sv, as_h2(w1.w), acc[7]);
  }
  if (!FINAL) {
    float* orow = outp + gr * 64 + h * 8;
    float4 v0, v1;
    v0.x = acc[0]; v0.y = acc[1]; v0.z = acc[2]; v0.w = acc[3];
    v1.x = acc[4]; v1.y = acc[5]; v1.z = acc[6]; v1.w = acc[7];
    *(float4*)orow = v0;
    *(float4*)(orow + 4) = v1;
  } else {
    __syncthreads();   // all sU reads done; reuse for transpose staging
#pragma unroll
    for (int j = 0; j < 4; ++j)
      sU[r * 33 + h * 4 + j] = h2u(pack2(acc[2 * j], acc[2 * j + 1]));
    __syncthreads();
    for (int i = t; i < 4096; i += 512) {
      int c = i >> 6, rr = i & 63;
      half2_t pr = as_h2(sU[rr * 33 + (c >> 1)]);
      float val = (c & 1) ? (float)pr.y : (float)pr.x;
      outp[((size_t)(b * 64 + c)) * NPIX + (size_t)tileb * 64 + rr] = val;
    }
  }
}

// ---------------------------------------------------------------------------
extern "C" void kernel_launch(void* const* d_in, const int* in_sizes, int n_in,
                              void* d_out, int out_size, void* d_ws, size_t ws_size,
                              hipStream_t stream) {
  const float* x1 = (const float*)d_in[0];
  const float* x2 = (const float*)d_in[1];
  const float *qw[4], *kvw[4], *pwv[4], *pbv[4], *srw[4], *srb[4], *lng[4], *lnb[4];
  for (int i = 0; i < 4; ++i) {
    const int base = 2 + i * 8;
    qw[i]  = (const float*)d_in[base + 0];
    kvw[i] = (const float*)d_in[base + 1];
    pwv[i] = (const float*)d_in[base + 2];
    pbv[i] = (const float*)d_in[base + 3];
    srw[i] = (const float*)d_in[base + 4];
    srb[i] = (const float*)d_in[base + 5];
    lng[i] = (const float*)d_in[base + 6];
    lnb[i] = (const float*)d_in[base + 7];
  }
  const float* fpw = (const float*)d_in[34];
  const float* fpb = (const float*)d_in[35];
  float* out = (float*)d_out;

  char* ws = (char*)d_ws;
  const size_t SZ = (size_t)2 * NPIX * 64 * 4;       // 6,422,528 B
  float* slot0 = (float*)(ws);
  float* slot1 = (float*)(ws + SZ);
  float* slot2 = (float*)(ws + 2 * SZ);
  size_t off = 3 * SZ;
  float* wt    = (float*)(ws + off); off += 4u * 1048576;
  float* part  = (float*)(ws + off); off += 802816;
  _Float16* kbuf = (_Float16*)(ws + off); off += 50176;
  _Float16* vbuf = (_Float16*)(ws + off); off += 50176;
  uint* pwh    = (uint*)(ws + off); off += 4 * 2048 * 4;
  float* pbc   = (float*)(ws + off); off += 256;

  float* xf1 = slot0; float* xf2 = slot1;
  float* abuf = slot2; float* bbuf = slot0; float* cbuf = slot1;

  k_prep<<<1044, 256, 0, stream>>>(x1, x2, xf1, xf2,
                                   srw[0], srw[1], srw[2], srw[3], wt,
                                   fpw, fpb, pwv[3], pbv[3],
                                   pwv[0], pwv[1], pwv[2], pwh, pbc);

  const float* xqs[4] = {xf1, xf2, bbuf, abuf};
  const float* kvs[4] = {xf1, abuf, bbuf, cbuf};
  float* outs[3]      = {abuf, bbuf, cbuf};
  for (int i = 0; i < 4; ++i) {
    k_conv<<<392, 256, 0, stream>>>(kvs[i], wt + i * 262144, part);
    k_lnkv<<<392, 128, 0, stream>>>(part, srb[i], lng[i], lnb[i], kvw[i], kbuf, vbuf);
    if (i < 3)
      k_score_out<false><<<392, 512, 0, stream>>>(xqs[i], qw[i], kbuf, vbuf,
                                                  pwh + i * 2048, pbv[i], outs[i]);
    else
      k_score_out<true><<<392, 512, 0, stream>>>(xqs[3], qw[3], kbuf, vbuf,
                                                 pwh + 3 * 2048, pbc, out);
  }
}